// Round 4
// baseline (849.847 us; speedup 1.0000x reference)
//
#include <hip/hip_runtime.h>

#define D 128
#define NNODES 100000
#define NEDGES 1600000
#define BN_EPS 1e-5f
#define NB_STATS 2048
#define NBLK_P 391   // ceil(NNODES/256)

// Scratch layout, offsets in float slots RELATIVE to scratch base `sb`.
// sb = d_ws when ws_size is large enough (copy overlapped into kernels),
// else the E_X region of d_out (copy issued last, overwrites scratch).
#define OFF_AX     0          // 12.8M f32
#define OFF_BX16   12800000   // 12.8M bf16 = 6.4M slots
#define OFF_ESRC   19200000   // 1.6M int
#define OFF_ORDER  20800000   // 1.6M int
#define OFF_INDEG  22400000   // 100k int
#define OFF_ROWS   22510000   // 100001 int
#define OFF_LEXC   22620000   // 100k int
#define OFF_BPART  22730000   // 512 int
#define OFF_BSCAN  22731000   // 512 int
#define OFF_PSUM   22740000   // 2048*128 f32
#define OFF_PSQ    23010000   // 2048*128 f32
#define OFF_SCALE  23280000   // 128
#define OFF_SHIFT  23280128   // 128
#define WS_NEED_BYTES 93200000ull

// main-block counts (grid = main + copy blocks)
#define MAIN_GEMM 512
#define MAIN_EDGE 2048
#define MAIN_AGG  2048
#define MAIN_FIN  2048

// E_X copy chunk boundaries in float4 units (total NEDGES*D/4 = 51.2M)
#define C_GEMM0   0L
#define C_GEMM1   16000000L
#define C_HIST1   21000000L
#define C_SCAN1   22000000L
#define C_SCAN2   23000000L
#define C_SCAN3   24000000L
#define C_FILL1   29000000L
#define C_AGG1    46000000L
#define C_BN1     48000000L
#define C_FIN1    51200000L

static __device__ __forceinline__ unsigned short f2bf(float f) {
    unsigned int u = __float_as_uint(f);
    u = (u + 0x7FFF + ((u >> 16) & 1)) >> 16;   // RNE, finite data
    return (unsigned short)u;
}
static __device__ __forceinline__ float bf_lo(unsigned v) {
    return __uint_as_float(v << 16);
}
static __device__ __forceinline__ float bf_hi(unsigned v) {
    return __uint_as_float(v & 0xFFFF0000u);
}

// Streaming copy of E_X float4 range [c0,c1) by copy-blocks cb of ncb.
static __device__ __forceinline__ void ex_copy(
    const float4* __restrict__ s, float4* __restrict__ d,
    long c0, long c1, int cb, int ncb)
{
    for (long i = c0 + (long)cb * blockDim.x + threadIdx.x; i < c1;
         i += (long)ncb * blockDim.x)
        d[i] = s[i];
}

// ---------------------------------------------------------------------------
// GEMM: Y[i,d] = sum_k X[i,k] * W[d,k] + bias[d]
// Even blocks -> A (f32 AX), odd blocks -> B (bf16 BX16).
// Blocks >= MAIN_GEMM stream the E_X copy.
// ---------------------------------------------------------------------------
__global__ __launch_bounds__(256, 2) void gemm2_kernel(
    const float* __restrict__ X,
    const float* __restrict__ Aw, const float* __restrict__ Ab,
    const float* __restrict__ Bw, const float* __restrict__ Bb,
    float* __restrict__ AX, unsigned short* __restrict__ BX16,
    const float4* __restrict__ exs, float4* __restrict__ exd,
    long c0, long c1)
{
    if (blockIdx.x >= MAIN_GEMM) {
        ex_copy(exs, exd, c0, c1, blockIdx.x - MAIN_GEMM,
                gridDim.x - MAIN_GEMM);
        return;
    }
    const bool isB = (blockIdx.x & 1);
    const float* __restrict__ W    = isB ? Bw : Aw;
    const float* __restrict__ bias = isB ? Bb : Ab;

    __shared__ float Ws[D * 132];
    const float4* W4 = (const float4*)W;
    for (int i = threadIdx.x; i < D * D / 4; i += 256) {
        int d  = i >> 5;
        int k4 = i & 31;
        float4 w = W4[i];
        *(float4*)&Ws[d * 132 + 4 * k4] = w;
    }
    __syncthreads();

    const int rg = threadIdx.x >> 5;   // 0..7  -> 4 rows each
    const int cg = threadIdx.x & 31;   // 0..31 -> cols cg+32j

    float b[4];
#pragma unroll
    for (int j = 0; j < 4; ++j) b[j] = bias[cg + 32 * j];

    const int ntiles = NNODES / 32;    // 3125 exact
    for (int t = (blockIdx.x >> 1); t < ntiles; t += (MAIN_GEMM >> 1)) {
        const int row0 = t * 32 + rg * 4;
        float acc[4][4];
#pragma unroll
        for (int r = 0; r < 4; ++r)
#pragma unroll
            for (int j = 0; j < 4; ++j) acc[r][j] = b[j];

        const float* xbase = X + (size_t)row0 * D;
#pragma unroll 4
        for (int k = 0; k < D; k += 4) {
            float4 xr[4];
#pragma unroll
            for (int r = 0; r < 4; ++r)
                xr[r] = *(const float4*)&xbase[r * D + k];
            float4 wv[4];
#pragma unroll
            for (int j = 0; j < 4; ++j)
                wv[j] = *(const float4*)&Ws[(cg + 32 * j) * 132 + k];
#pragma unroll
            for (int r = 0; r < 4; ++r)
#pragma unroll
                for (int j = 0; j < 4; ++j)
                    acc[r][j] += xr[r].x * wv[j].x + xr[r].y * wv[j].y +
                                 xr[r].z * wv[j].z + xr[r].w * wv[j].w;
        }
        if (isB) {
#pragma unroll
            for (int r = 0; r < 4; ++r) {
                unsigned short* yrow = BX16 + (size_t)(row0 + r) * D;
#pragma unroll
                for (int j = 0; j < 4; ++j)
                    yrow[cg + 32 * j] = f2bf(acc[r][j]);
            }
        } else {
#pragma unroll
            for (int r = 0; r < 4; ++r) {
                float* yrow = AX + (size_t)(row0 + r) * D;
#pragma unroll
                for (int j = 0; j < 4; ++j) yrow[cg + 32 * j] = acc[r][j];
            }
        }
    }
}

// ---------------------------------------------------------------------------
// Histogram + per-edge rank: order[e] = indeg[dst[e]]++ (int atomics).
// ---------------------------------------------------------------------------
__global__ __launch_bounds__(256) void hist_kernel(
    const int* __restrict__ dst, int* __restrict__ indeg,
    int* __restrict__ order,
    const float4* __restrict__ exs, float4* __restrict__ exd,
    long c0, long c1)
{
    if (blockIdx.x >= MAIN_EDGE) {
        ex_copy(exs, exd, c0, c1, blockIdx.x - MAIN_EDGE,
                gridDim.x - MAIN_EDGE);
        return;
    }
    for (int e = blockIdx.x * 256 + threadIdx.x; e < NEDGES;
         e += MAIN_EDGE * 256)
        order[e] = atomicAdd(&indeg[dst[e]], 1);
}

// ---------------------------------------------------------------------------
// Parallel scan: (1) per-block local exclusive scan + block totals,
// (2) scan of block totals, (3) add block prefix -> rows.
// ---------------------------------------------------------------------------
__global__ __launch_bounds__(256) void scan1_kernel(
    const int* __restrict__ indeg, int* __restrict__ lexc,
    int* __restrict__ bpart,
    const float4* __restrict__ exs, float4* __restrict__ exd,
    long c0, long c1)
{
    if (blockIdx.x >= NBLK_P) {
        ex_copy(exs, exd, c0, c1, blockIdx.x - NBLK_P, gridDim.x - NBLK_P);
        return;
    }
    __shared__ int ls[256];
    const int i = blockIdx.x * 256 + threadIdx.x;
    const int v = (i < NNODES) ? indeg[i] : 0;
    ls[threadIdx.x] = v;
    __syncthreads();
    for (int off = 1; off < 256; off <<= 1) {
        int u = (threadIdx.x >= off) ? ls[threadIdx.x - off] : 0;
        __syncthreads();
        ls[threadIdx.x] += u;
        __syncthreads();
    }
    if (i < NNODES) lexc[i] = ls[threadIdx.x] - v;
    if (threadIdx.x == 255) bpart[blockIdx.x] = ls[255];
}

__global__ __launch_bounds__(512) void scan2_kernel(
    const int* __restrict__ bpart, int* __restrict__ bscan,
    int* __restrict__ rows,
    const float4* __restrict__ exs, float4* __restrict__ exd,
    long c0, long c1)
{
    if (blockIdx.x >= 1) {
        ex_copy(exs, exd, c0, c1, blockIdx.x - 1, gridDim.x - 1);
        return;
    }
    __shared__ int ls[512];
    const int t = threadIdx.x;
    const int v = (t < NBLK_P) ? bpart[t] : 0;
    ls[t] = v;
    __syncthreads();
    for (int off = 1; off < 512; off <<= 1) {
        int u = (t >= off) ? ls[t - off] : 0;
        __syncthreads();
        ls[t] += u;
        __syncthreads();
    }
    if (t < NBLK_P) bscan[t] = ls[t] - v;    // exclusive
    if (t == 0) rows[NNODES] = NEDGES;
}

__global__ __launch_bounds__(256) void scan3_kernel(
    const int* __restrict__ lexc, const int* __restrict__ bscan,
    int* __restrict__ rows,
    const float4* __restrict__ exs, float4* __restrict__ exd,
    long c0, long c1)
{
    if (blockIdx.x >= NBLK_P) {
        ex_copy(exs, exd, c0, c1, blockIdx.x - NBLK_P, gridDim.x - NBLK_P);
        return;
    }
    const int i = blockIdx.x * 256 + threadIdx.x;
    if (i < NNODES) rows[i] = bscan[blockIdx.x] + lexc[i];
}

// ---------------------------------------------------------------------------
// Fill CSR without atomics: esrc[rows[dst[e]] + order[e]] = src[e].
// ---------------------------------------------------------------------------
__global__ __launch_bounds__(256) void fill_kernel(
    const int* __restrict__ src, const int* __restrict__ dst,
    const int* __restrict__ rows, const int* __restrict__ order,
    int* __restrict__ esrc,
    const float4* __restrict__ exs, float4* __restrict__ exd,
    long c0, long c1)
{
    if (blockIdx.x >= MAIN_EDGE) {
        ex_copy(exs, exd, c0, c1, blockIdx.x - MAIN_EDGE,
                gridDim.x - MAIN_EDGE);
        return;
    }
    for (int e = blockIdx.x * 256 + threadIdx.x; e < NEDGES;
         e += MAIN_EDGE * 256) {
        esrc[rows[dst[e]] + order[e]] = src[e];
    }
}

// ---------------------------------------------------------------------------
// Gather-aggregate + fused Hpre: one wave per node, 64 lanes x 2 cols.
// BX is bf16 (one u32 per lane = 2 cols). Edge loop unrolled x4 for MLP.
// ---------------------------------------------------------------------------
__global__ __launch_bounds__(256, 4) void agg_kernel(
    const float* __restrict__ AX, const unsigned* __restrict__ BX32,
    const float* __restrict__ X, const float* __restrict__ snorm,
    const int* __restrict__ rows, const int* __restrict__ esrc,
    float* __restrict__ Hpre, float* __restrict__ psum,
    float* __restrict__ psq,
    const float4* __restrict__ exs, float4* __restrict__ exd,
    long c0, long c1)
{
    if (blockIdx.x >= MAIN_AGG) {
        ex_copy(exs, exd, c0, c1, blockIdx.x - MAIN_AGG,
                gridDim.x - MAIN_AGG);
        return;
    }
    const int w    = threadIdx.x >> 6;   // wave in block, 0..3
    const int lane = threadIdx.x & 63;
    const int cc0  = lane * 2;
    float ps0 = 0.f, ps1 = 0.f, q0 = 0.f, q1 = 0.f;

    for (int i = blockIdx.x * 4 + w; i < NNODES; i += MAIN_AGG * 4) {
        const int rs = rows[i];
        const int re = rows[i + 1];
        float ax, ay;
        if (re > rs) {
            float2 a0 = *(const float2*)&AX[(size_t)i * D + cc0];
            ax = a0.x; ay = a0.y;
            int e = rs;
            for (; e + 4 <= re; e += 4) {
                const int s0 = esrc[e + 0], s1 = esrc[e + 1];
                const int s2 = esrc[e + 2], s3 = esrc[e + 3];
                const unsigned v0 = BX32[s0 * 64 + lane];
                const unsigned v1 = BX32[s1 * 64 + lane];
                const unsigned v2 = BX32[s2 * 64 + lane];
                const unsigned v3 = BX32[s3 * 64 + lane];
                ax += bf_lo(v0) + bf_lo(v1) + bf_lo(v2) + bf_lo(v3);
                ay += bf_hi(v0) + bf_hi(v1) + bf_hi(v2) + bf_hi(v3);
            }
            for (; e < re; ++e) {
                const unsigned v = BX32[esrc[e] * 64 + lane];
                ax += bf_lo(v);
                ay += bf_hi(v);
            }
        } else {
            float2 x0 = *(const float2*)&X[(size_t)i * D + cc0];
            ax = x0.x; ay = x0.y;
        }
        const float sn = snorm[i];
        ax *= sn; ay *= sn;
        *(float2*)&Hpre[(size_t)i * D + cc0] = make_float2(ax, ay);
        ps0 += ax; ps1 += ay;
        q0  += ax * ax; q1 += ay * ay;
    }

    __shared__ float sp[4][D], sq[4][D];
    sp[w][cc0] = ps0; sp[w][cc0 + 1] = ps1;
    sq[w][cc0] = q0;  sq[w][cc0 + 1] = q1;
    __syncthreads();
    if (threadIdx.x < D) {
        const int c = threadIdx.x;
        psum[blockIdx.x * D + c] = sp[0][c] + sp[1][c] + sp[2][c] + sp[3][c];
        psq [blockIdx.x * D + c] = sq[0][c] + sq[1][c] + sq[2][c] + sq[3][c];
    }
}

// ---------------------------------------------------------------------------
// Reduce partials -> scale/shift for fused BN.
// ---------------------------------------------------------------------------
__global__ __launch_bounds__(1024) void bnstats_kernel(
    const float* __restrict__ psum, const float* __restrict__ psq,
    const float* __restrict__ gamma, const float* __restrict__ beta,
    float* __restrict__ scale, float* __restrict__ shift,
    const float4* __restrict__ exs, float4* __restrict__ exd,
    long c0, long c1)
{
    if (blockIdx.x >= 1) {
        ex_copy(exs, exd, c0, c1, blockIdx.x - 1, gridDim.x - 1);
        return;
    }
    const int c = threadIdx.x & 127;
    const int g = threadIdx.x >> 7;   // 0..7
    float s = 0.f, q = 0.f;
    for (int b = g; b < NB_STATS; b += 8) {
        s += psum[b * D + c];
        q += psq [b * D + c];
    }
    __shared__ float ls[8][D], lq[8][D];
    ls[g][c] = s;
    lq[g][c] = q;
    __syncthreads();
    if (threadIdx.x < D) {
        float S = 0.f, Q = 0.f;
#pragma unroll
        for (int g2 = 0; g2 < 8; ++g2) { S += ls[g2][c]; Q += lq[g2][c]; }
        const float inv_n = 1.0f / (float)NNODES;
        float mean = S * inv_n;
        float var  = Q * inv_n - mean * mean;
        float sc   = rsqrtf(var + BN_EPS) * gamma[c];
        scale[c] = sc;
        shift[c] = beta[c] - mean * sc;
    }
}

// ---------------------------------------------------------------------------
// out = X + relu(Hpre * scale + shift), in place over the H region.
// ---------------------------------------------------------------------------
__global__ __launch_bounds__(256) void final_kernel(
    const float* __restrict__ Hpre, const float* __restrict__ X,
    const float* __restrict__ scale, const float* __restrict__ shift,
    float* __restrict__ out,
    const float4* __restrict__ exs, float4* __restrict__ exd,
    long c0, long c1)
{
    if (blockIdx.x >= MAIN_FIN) {
        ex_copy(exs, exd, c0, c1, blockIdx.x - MAIN_FIN,
                gridDim.x - MAIN_FIN);
        return;
    }
    const int total = NNODES * D / 4;
    for (int i = blockIdx.x * 256 + threadIdx.x; i < total;
         i += MAIN_FIN * 256) {
        float4 h = ((const float4*)Hpre)[i];
        float4 x = ((const float4*)X)[i];
        int d0 = (i * 4) & 127;
        float4 r;
        r.x = x.x + fmaxf(0.f, h.x * scale[d0 + 0] + shift[d0 + 0]);
        r.y = x.y + fmaxf(0.f, h.y * scale[d0 + 1] + shift[d0 + 1]);
        r.z = x.z + fmaxf(0.f, h.z * scale[d0 + 2] + shift[d0 + 2]);
        r.w = x.w + fmaxf(0.f, h.w * scale[d0 + 3] + shift[d0 + 3]);
        ((float4*)out)[i] = r;
    }
}

extern "C" void kernel_launch(void* const* d_in, const int* in_sizes, int n_in,
                              void* d_out, int out_size, void* d_ws, size_t ws_size,
                              hipStream_t stream)
{
    const float* X       = (const float*)d_in[0];
    const float* E_X     = (const float*)d_in[1];
    const float* snorm_n = (const float*)d_in[2];
    const int*   src     = (const int*)d_in[4];
    const int*   dst     = (const int*)d_in[5];
    const float* A_w     = (const float*)d_in[6];
    const float* A_b     = (const float*)d_in[7];
    const float* B_w     = (const float*)d_in[8];
    const float* B_b     = (const float*)d_in[9];
    const float* gamma   = (const float*)d_in[10];
    const float* beta    = (const float*)d_in[11];

    float* out = (float*)d_out;
    const bool use_ws = (ws_size >= WS_NEED_BYTES);
    float* sb = use_ws ? (float*)d_ws : (out + (size_t)NNODES * D);

    float*          AX    = sb + OFF_AX;
    unsigned short* BX16  = (unsigned short*)(sb + OFF_BX16);
    int*            esrc  = (int*)(sb + OFF_ESRC);
    int*            order = (int*)(sb + OFF_ORDER);
    int*            indeg = (int*)(sb + OFF_INDEG);
    int*            rows  = (int*)(sb + OFF_ROWS);
    int*            lexc  = (int*)(sb + OFF_LEXC);
    int*            bpart = (int*)(sb + OFF_BPART);
    int*            bscan = (int*)(sb + OFF_BSCAN);
    float*          psum  = sb + OFF_PSUM;
    float*          psq   = sb + OFF_PSQ;
    float*          scale = sb + OFF_SCALE;
    float*          shift = sb + OFF_SHIFT;

    const float4* exs = (const float4*)E_X;
    float4*       exd = (float4*)(out + (size_t)NNODES * D);

    hipMemsetAsync(indeg, 0, NNODES * sizeof(int), stream);

    if (use_ws) {
        // Copy overlapped: extra blocks on every launch stream E_X -> out.
        gemm2_kernel<<<MAIN_GEMM + 1024, 256, 0, stream>>>(
            X, A_w, A_b, B_w, B_b, AX, BX16, exs, exd, C_GEMM0, C_GEMM1);
        hist_kernel<<<MAIN_EDGE + 512, 256, 0, stream>>>(
            dst, indeg, order, exs, exd, C_GEMM1, C_HIST1);
        scan1_kernel<<<NBLK_P + 256, 256, 0, stream>>>(
            indeg, lexc, bpart, exs, exd, C_HIST1, C_SCAN1);
        scan2_kernel<<<1 + 256, 512, 0, stream>>>(
            bpart, bscan, rows, exs, exd, C_SCAN1, C_SCAN2);
        scan3_kernel<<<NBLK_P + 256, 256, 0, stream>>>(
            lexc, bscan, rows, exs, exd, C_SCAN2, C_SCAN3);
        fill_kernel<<<MAIN_EDGE + 512, 256, 0, stream>>>(
            src, dst, rows, order, esrc, exs, exd, C_SCAN3, C_FILL1);
        agg_kernel<<<MAIN_AGG + 1024, 256, 0, stream>>>(
            AX, (const unsigned*)BX16, X, snorm_n, rows, esrc,
            out, psum, psq, exs, exd, C_FILL1, C_AGG1);
        bnstats_kernel<<<1 + 256, 1024, 0, stream>>>(
            psum, psq, gamma, beta, scale, shift, exs, exd, C_AGG1, C_BN1);
        final_kernel<<<MAIN_FIN + 256, 256, 0, stream>>>(
            out, X, scale, shift, out, exs, exd, C_BN1, C_FIN1);
    } else {
        // Fallback: scratch in out's E_X region, tail copy overwrites it.
        gemm2_kernel<<<MAIN_GEMM, 256, 0, stream>>>(
            X, A_w, A_b, B_w, B_b, AX, BX16, exs, exd, 0, 0);
        hist_kernel<<<MAIN_EDGE, 256, 0, stream>>>(
            dst, indeg, order, exs, exd, 0, 0);
        scan1_kernel<<<NBLK_P, 256, 0, stream>>>(
            indeg, lexc, bpart, exs, exd, 0, 0);
        scan2_kernel<<<1, 512, 0, stream>>>(
            bpart, bscan, rows, exs, exd, 0, 0);
        scan3_kernel<<<NBLK_P, 256, 0, stream>>>(
            lexc, bscan, rows, exs, exd, 0, 0);
        fill_kernel<<<MAIN_EDGE, 256, 0, stream>>>(
            src, dst, rows, order, esrc, exs, exd, 0, 0);
        agg_kernel<<<MAIN_AGG, 256, 0, stream>>>(
            AX, (const unsigned*)BX16, X, snorm_n, rows, esrc,
            out, psum, psq, exs, exd, 0, 0);
        bnstats_kernel<<<1, 1024, 0, stream>>>(
            psum, psq, gamma, beta, scale, shift, exs, exd, 0, 0);
        final_kernel<<<MAIN_FIN, 256, 0, stream>>>(
            out, X, scale, shift, out, exs, exd, 0, 0);
        hipMemcpyAsync(exd, exs, (size_t)NEDGES * D * sizeof(float),
                       hipMemcpyDeviceToDevice, stream);
    }
}

// Round 5
// 748.837 us; speedup vs baseline: 1.1349x; 1.1349x over previous
//
#include <hip/hip_runtime.h>

#define D 128
#define NNODES 100000
#define NEDGES 1600000
#define BN_EPS 1e-5f
#define NB_STATS 2048
#define NBLK_P 391   // ceil(NNODES/256)

// Scratch layout, offsets in float slots RELATIVE to scratch base `sb`.
// sb = d_ws when ws_size is large enough (copy overlapped into kernels),
// else the E_X region of d_out (copy issued last, overwrites scratch).
#define OFF_AX     0          // 12.8M f32
#define OFF_BX16   12800000   // 12.8M bf16 = 6.4M slots
#define OFF_ESRC   19200000   // 1.6M int
#define OFF_ORDER  20800000   // 1.6M int
#define OFF_INDEG  22400000   // 100k int
#define OFF_ROWS   22510000   // 100001 int
#define OFF_LEXC   22620000   // 100k int
#define OFF_BPART  22730000   // 512 int
#define OFF_BSCAN  22731000   // 512 int
#define OFF_PSUM   22740000   // 2048*128 f32
#define OFF_PSQ    23010000   // 2048*128 f32
#define OFF_SCALE  23280000   // 128
#define OFF_SHIFT  23280128   // 128
#define WS_NEED_BYTES 93200000ull

#define MAIN_GEMM 512
#define MAIN_EDGE 2048
#define MAIN_AGG  2048
#define MAIN_FIN  2048

// E_X copy budget in float4 units (total NEDGES*D/4 = 51,200,000).
// Interleaved INSIDE compute blocks: gemm 12 tile-iters x 2048/blk,
// hist/fill 3 iters x 1024/blk. Tail memcpy covers the rest.
#define GEMM_BSZ   24576L                 // per-block float4 (12*2048)
#define GEMM_TOTAL (512L * GEMM_BSZ)      // 12,582,912
#define HIST_BSZ   3072L                  // per-block float4 (3*1024)
#define HIST_START GEMM_TOTAL
#define HIST_TOTAL (2048L * HIST_BSZ)     // 6,291,456
#define FILL_START (HIST_START + HIST_TOTAL)
#define FILL_TOTAL (2048L * HIST_BSZ)
#define TAIL_START (FILL_START + FILL_TOTAL)   // 25,165,824
#define C_TOTAL    51200000L

static __device__ __forceinline__ unsigned short f2bf(float f) {
    unsigned int u = __float_as_uint(f);
    u = (u + 0x7FFF + ((u >> 16) & 1)) >> 16;   // RNE, finite data
    return (unsigned short)u;
}
static __device__ __forceinline__ float bf_lo(unsigned v) {
    return __uint_as_float(v << 16);
}
static __device__ __forceinline__ float bf_hi(unsigned v) {
    return __uint_as_float(v & 0xFFFF0000u);
}

// ---------------------------------------------------------------------------
// GEMM: Y[i,d] = sum_k X[i,k] * W[d,k] + bias[d]
// Even blocks -> A (f32 AX), odd blocks -> B (bf16 BX16).
// Each block interleaves an 8-float4/thread E_X copy stripe per tile iter.
// ---------------------------------------------------------------------------
__global__ __launch_bounds__(256, 2) void gemm2_kernel(
    const float* __restrict__ X,
    const float* __restrict__ Aw, const float* __restrict__ Ab,
    const float* __restrict__ Bw, const float* __restrict__ Bb,
    float* __restrict__ AX, unsigned short* __restrict__ BX16,
    const float4* __restrict__ exs, float4* __restrict__ exd,
    long bsz)
{
    const bool isB = (blockIdx.x & 1);
    const float* __restrict__ W    = isB ? Bw : Aw;
    const float* __restrict__ bias = isB ? Bb : Ab;

    long cur  = (long)blockIdx.x * bsz + threadIdx.x;
    const long bend = (long)blockIdx.x * bsz + bsz;

    __shared__ float Ws[D * 132];
    const float4* W4 = (const float4*)W;
    for (int i = threadIdx.x; i < D * D / 4; i += 256) {
        int d  = i >> 5;
        int k4 = i & 31;
        float4 w = W4[i];
        *(float4*)&Ws[d * 132 + 4 * k4] = w;
    }
    __syncthreads();

    const int rg = threadIdx.x >> 5;   // 0..7  -> 4 rows each
    const int cg = threadIdx.x & 31;   // 0..31 -> cols cg+32j

    float b[4];
#pragma unroll
    for (int j = 0; j < 4; ++j) b[j] = bias[cg + 32 * j];

    const int ntiles = NNODES / 32;    // 3125 exact
    for (int t = (blockIdx.x >> 1); t < ntiles; t += (MAIN_GEMM >> 1)) {
        const int row0 = t * 32 + rg * 4;
        float acc[4][4];
#pragma unroll
        for (int r = 0; r < 4; ++r)
#pragma unroll
            for (int j = 0; j < 4; ++j) acc[r][j] = b[j];

        const float* xbase = X + (size_t)row0 * D;
#pragma unroll 4
        for (int k = 0; k < D; k += 4) {
            float4 xr[4];
#pragma unroll
            for (int r = 0; r < 4; ++r)
                xr[r] = *(const float4*)&xbase[r * D + k];
            float4 wv[4];
#pragma unroll
            for (int j = 0; j < 4; ++j)
                wv[j] = *(const float4*)&Ws[(cg + 32 * j) * 132 + k];
#pragma unroll
            for (int r = 0; r < 4; ++r)
#pragma unroll
                for (int j = 0; j < 4; ++j)
                    acc[r][j] += xr[r].x * wv[j].x + xr[r].y * wv[j].y +
                                 xr[r].z * wv[j].z + xr[r].w * wv[j].w;
        }
        if (isB) {
#pragma unroll
            for (int r = 0; r < 4; ++r) {
                unsigned short* yrow = BX16 + (size_t)(row0 + r) * D;
#pragma unroll
                for (int j = 0; j < 4; ++j)
                    yrow[cg + 32 * j] = f2bf(acc[r][j]);
            }
        } else {
#pragma unroll
            for (int r = 0; r < 4; ++r) {
                float* yrow = AX + (size_t)(row0 + r) * D;
#pragma unroll
                for (int j = 0; j < 4; ++j) yrow[cg + 32 * j] = acc[r][j];
            }
        }
        // interleaved E_X copy stripe: 8 float4 per thread
#pragma unroll
        for (int j = 0; j < 8; ++j) {
            long idx = cur + j * 256;
            if (idx < bend) exd[idx] = exs[idx];
        }
        cur += 2048;
    }
}

// ---------------------------------------------------------------------------
// Histogram + per-edge rank: order[e] = indeg[dst[e]]++ (int atomics),
// with interleaved E_X copy (4 float4 per thread per iter).
// ---------------------------------------------------------------------------
__global__ __launch_bounds__(256) void hist_kernel(
    const int* __restrict__ dst, int* __restrict__ indeg,
    int* __restrict__ order,
    const float4* __restrict__ exs, float4* __restrict__ exd,
    long cstart, long cb)
{
    long cur  = cstart + (long)blockIdx.x * cb + threadIdx.x;
    const long bend = cstart + (long)blockIdx.x * cb + cb;
    int e = blockIdx.x * 256 + threadIdx.x;
#pragma unroll 1
    for (int it = 0; it < 4; ++it) {
        if (e < NEDGES) order[e] = atomicAdd(&indeg[dst[e]], 1);
#pragma unroll
        for (int j = 0; j < 4; ++j) {
            long idx = cur + j * 256;
            if (idx < bend) exd[idx] = exs[idx];
        }
        cur += 1024;
        e   += MAIN_EDGE * 256;
    }
}

// ---------------------------------------------------------------------------
// Parallel scan: (1) per-block local exclusive scan + block totals,
// (2) scan of block totals, (3) add block prefix -> rows.
// ---------------------------------------------------------------------------
__global__ __launch_bounds__(256) void scan1_kernel(
    const int* __restrict__ indeg, int* __restrict__ lexc,
    int* __restrict__ bpart)
{
    __shared__ int ls[256];
    const int i = blockIdx.x * 256 + threadIdx.x;
    const int v = (i < NNODES) ? indeg[i] : 0;
    ls[threadIdx.x] = v;
    __syncthreads();
    for (int off = 1; off < 256; off <<= 1) {
        int u = (threadIdx.x >= off) ? ls[threadIdx.x - off] : 0;
        __syncthreads();
        ls[threadIdx.x] += u;
        __syncthreads();
    }
    if (i < NNODES) lexc[i] = ls[threadIdx.x] - v;
    if (threadIdx.x == 255) bpart[blockIdx.x] = ls[255];
}

__global__ __launch_bounds__(512) void scan2_kernel(
    const int* __restrict__ bpart, int* __restrict__ bscan,
    int* __restrict__ rows)
{
    __shared__ int ls[512];
    const int t = threadIdx.x;
    const int v = (t < NBLK_P) ? bpart[t] : 0;
    ls[t] = v;
    __syncthreads();
    for (int off = 1; off < 512; off <<= 1) {
        int u = (t >= off) ? ls[t - off] : 0;
        __syncthreads();
        ls[t] += u;
        __syncthreads();
    }
    if (t < NBLK_P) bscan[t] = ls[t] - v;    // exclusive
    if (t == 0) rows[NNODES] = NEDGES;
}

__global__ __launch_bounds__(256) void scan3_kernel(
    const int* __restrict__ lexc, const int* __restrict__ bscan,
    int* __restrict__ rows)
{
    const int i = blockIdx.x * 256 + threadIdx.x;
    if (i < NNODES) rows[i] = bscan[blockIdx.x] + lexc[i];
}

// ---------------------------------------------------------------------------
// Fill CSR without atomics: esrc[rows[dst[e]] + order[e]] = src[e],
// with interleaved E_X copy.
// ---------------------------------------------------------------------------
__global__ __launch_bounds__(256) void fill_kernel(
    const int* __restrict__ src, const int* __restrict__ dst,
    const int* __restrict__ rows, const int* __restrict__ order,
    int* __restrict__ esrc,
    const float4* __restrict__ exs, float4* __restrict__ exd,
    long cstart, long cb)
{
    long cur  = cstart + (long)blockIdx.x * cb + threadIdx.x;
    const long bend = cstart + (long)blockIdx.x * cb + cb;
    int e = blockIdx.x * 256 + threadIdx.x;
#pragma unroll 1
    for (int it = 0; it < 4; ++it) {
        if (e < NEDGES) esrc[rows[dst[e]] + order[e]] = src[e];
#pragma unroll
        for (int j = 0; j < 4; ++j) {
            long idx = cur + j * 256;
            if (idx < bend) exd[idx] = exs[idx];
        }
        cur += 1024;
        e   += MAIN_EDGE * 256;
    }
}

// ---------------------------------------------------------------------------
// Gather-aggregate + fused Hpre: one wave per node, 64 lanes x 2 cols.
// BX is bf16 (one u32 per lane = 2 cols). Pure compute (no copy: keeps
// BX16 cache-resident). High occupancy for latency hiding.
// ---------------------------------------------------------------------------
__global__ __launch_bounds__(256, 8) void agg_kernel(
    const float* __restrict__ AX, const unsigned* __restrict__ BX32,
    const float* __restrict__ X, const float* __restrict__ snorm,
    const int* __restrict__ rows, const int* __restrict__ esrc,
    float* __restrict__ Hpre, float* __restrict__ psum,
    float* __restrict__ psq)
{
    const int w    = threadIdx.x >> 6;   // wave in block, 0..3
    const int lane = threadIdx.x & 63;
    const int c0   = lane * 2;
    float ps0 = 0.f, ps1 = 0.f, q0 = 0.f, q1 = 0.f;

    for (int i = blockIdx.x * 4 + w; i < NNODES; i += MAIN_AGG * 4) {
        const int rs = rows[i];
        const int re = rows[i + 1];
        float ax, ay;
        if (re > rs) {
            float2 a0 = *(const float2*)&AX[(size_t)i * D + c0];
            ax = a0.x; ay = a0.y;
            int e = rs;
            for (; e + 4 <= re; e += 4) {
                const int s0 = esrc[e + 0], s1 = esrc[e + 1];
                const int s2 = esrc[e + 2], s3 = esrc[e + 3];
                const unsigned v0 = BX32[s0 * 64 + lane];
                const unsigned v1 = BX32[s1 * 64 + lane];
                const unsigned v2 = BX32[s2 * 64 + lane];
                const unsigned v3 = BX32[s3 * 64 + lane];
                ax += bf_lo(v0) + bf_lo(v1) + bf_lo(v2) + bf_lo(v3);
                ay += bf_hi(v0) + bf_hi(v1) + bf_hi(v2) + bf_hi(v3);
            }
            for (; e < re; ++e) {
                const unsigned v = BX32[esrc[e] * 64 + lane];
                ax += bf_lo(v);
                ay += bf_hi(v);
            }
        } else {
            float2 x0 = *(const float2*)&X[(size_t)i * D + c0];
            ax = x0.x; ay = x0.y;
        }
        const float sn = snorm[i];
        ax *= sn; ay *= sn;
        *(float2*)&Hpre[(size_t)i * D + c0] = make_float2(ax, ay);
        ps0 += ax; ps1 += ay;
        q0  += ax * ax; q1 += ay * ay;
    }

    __shared__ float sp[4][D], sq[4][D];
    sp[w][c0] = ps0; sp[w][c0 + 1] = ps1;
    sq[w][c0] = q0;  sq[w][c0 + 1] = q1;
    __syncthreads();
    if (threadIdx.x < D) {
        const int c = threadIdx.x;
        psum[blockIdx.x * D + c] = sp[0][c] + sp[1][c] + sp[2][c] + sp[3][c];
        psq [blockIdx.x * D + c] = sq[0][c] + sq[1][c] + sq[2][c] + sq[3][c];
    }
}

// ---------------------------------------------------------------------------
// Reduce partials -> scale/shift for fused BN.
// ---------------------------------------------------------------------------
__global__ __launch_bounds__(1024) void bnstats_kernel(
    const float* __restrict__ psum, const float* __restrict__ psq,
    const float* __restrict__ gamma, const float* __restrict__ beta,
    float* __restrict__ scale, float* __restrict__ shift)
{
    const int c = threadIdx.x & 127;
    const int g = threadIdx.x >> 7;   // 0..7
    float s = 0.f, q = 0.f;
    for (int b = g; b < NB_STATS; b += 8) {
        s += psum[b * D + c];
        q += psq [b * D + c];
    }
    __shared__ float ls[8][D], lq[8][D];
    ls[g][c] = s;
    lq[g][c] = q;
    __syncthreads();
    if (threadIdx.x < D) {
        float S = 0.f, Q = 0.f;
#pragma unroll
        for (int g2 = 0; g2 < 8; ++g2) { S += ls[g2][c]; Q += lq[g2][c]; }
        const float inv_n = 1.0f / (float)NNODES;
        float mean = S * inv_n;
        float var  = Q * inv_n - mean * mean;
        float sc   = rsqrtf(var + BN_EPS) * gamma[c];
        scale[c] = sc;
        shift[c] = beta[c] - mean * sc;
    }
}

// ---------------------------------------------------------------------------
// out = X + relu(Hpre * scale + shift), in place over the H region.
// ---------------------------------------------------------------------------
__global__ __launch_bounds__(256) void final_kernel(
    const float* __restrict__ Hpre, const float* __restrict__ X,
    const float* __restrict__ scale, const float* __restrict__ shift,
    float* __restrict__ out)
{
    const int total = NNODES * D / 4;
    for (int i = blockIdx.x * 256 + threadIdx.x; i < total;
         i += MAIN_FIN * 256) {
        float4 h = ((const float4*)Hpre)[i];
        float4 x = ((const float4*)X)[i];
        int d0 = (i * 4) & 127;
        float4 r;
        r.x = x.x + fmaxf(0.f, h.x * scale[d0 + 0] + shift[d0 + 0]);
        r.y = x.y + fmaxf(0.f, h.y * scale[d0 + 1] + shift[d0 + 1]);
        r.z = x.z + fmaxf(0.f, h.z * scale[d0 + 2] + shift[d0 + 2]);
        r.w = x.w + fmaxf(0.f, h.w * scale[d0 + 3] + shift[d0 + 3]);
        ((float4*)out)[i] = r;
    }
}

extern "C" void kernel_launch(void* const* d_in, const int* in_sizes, int n_in,
                              void* d_out, int out_size, void* d_ws, size_t ws_size,
                              hipStream_t stream)
{
    const float* X       = (const float*)d_in[0];
    const float* E_X     = (const float*)d_in[1];
    const float* snorm_n = (const float*)d_in[2];
    const int*   src     = (const int*)d_in[4];
    const int*   dst     = (const int*)d_in[5];
    const float* A_w     = (const float*)d_in[6];
    const float* A_b     = (const float*)d_in[7];
    const float* B_w     = (const float*)d_in[8];
    const float* B_b     = (const float*)d_in[9];
    const float* gamma   = (const float*)d_in[10];
    const float* beta    = (const float*)d_in[11];

    float* out = (float*)d_out;
    const bool use_ws = (ws_size >= WS_NEED_BYTES);
    float* sb = use_ws ? (float*)d_ws : (out + (size_t)NNODES * D);

    float*          AX    = sb + OFF_AX;
    unsigned short* BX16  = (unsigned short*)(sb + OFF_BX16);
    int*            esrc  = (int*)(sb + OFF_ESRC);
    int*            order = (int*)(sb + OFF_ORDER);
    int*            indeg = (int*)(sb + OFF_INDEG);
    int*            rows  = (int*)(sb + OFF_ROWS);
    int*            lexc  = (int*)(sb + OFF_LEXC);
    int*            bpart = (int*)(sb + OFF_BPART);
    int*            bscan = (int*)(sb + OFF_BSCAN);
    float*          psum  = sb + OFF_PSUM;
    float*          psq   = sb + OFF_PSQ;
    float*          scale = sb + OFF_SCALE;
    float*          shift = sb + OFF_SHIFT;

    const float4* exs = (const float4*)E_X;
    float4*       exd = (float4*)(out + (size_t)NNODES * D);

    // Copy budgets: interleaved in-block when scratch is in d_ws,
    // else everything via the tail memcpy (scratch aliases exd region).
    const long gemm_bsz  = use_ws ? GEMM_BSZ : 0;
    const long edge_cb   = use_ws ? HIST_BSZ : 0;
    const long tail_from = use_ws ? TAIL_START : 0;

    hipMemsetAsync(indeg, 0, NNODES * sizeof(int), stream);

    gemm2_kernel<<<MAIN_GEMM, 256, 0, stream>>>(
        X, A_w, A_b, B_w, B_b, AX, BX16, exs, exd, gemm_bsz);
    hist_kernel<<<MAIN_EDGE, 256, 0, stream>>>(
        dst, indeg, order, exs, exd, HIST_START, edge_cb);
    scan1_kernel<<<NBLK_P, 256, 0, stream>>>(indeg, lexc, bpart);
    scan2_kernel<<<1, 512, 0, stream>>>(bpart, bscan, rows);
    scan3_kernel<<<NBLK_P, 256, 0, stream>>>(lexc, bscan, rows);
    fill_kernel<<<MAIN_EDGE, 256, 0, stream>>>(
        src, dst, rows, order, esrc, exs, exd, FILL_START, edge_cb);
    agg_kernel<<<MAIN_AGG, 256, 0, stream>>>(
        AX, (const unsigned*)BX16, X, snorm_n, rows, esrc, out, psum, psq);
    bnstats_kernel<<<1, 1024, 0, stream>>>(psum, psq, gamma, beta,
                                           scale, shift);
    final_kernel<<<MAIN_FIN, 256, 0, stream>>>(out, X, scale, shift, out);

    hipMemcpyAsync(exd + tail_from, exs + tail_from,
                   (size_t)(C_TOTAL - tail_from) * sizeof(float4),
                   hipMemcpyDeviceToDevice, stream);
}